// Round 2
// baseline (1959.168 us; speedup 1.0000x reference)
//
#include <hip/hip_runtime.h>

// MSDeformAttn encoder layer, f32 pipeline, lean workspace (148.75 MiB).
#define DMODEL 256
#define NHEAD 8
#define NPOINT 4
#define NLEVEL 4
#define DHEAD 32
#define MLPD 1024
#define BSZ 2
#define LQTOK 21760
#define NTOK (BSZ * LQTOK)   // 43520
#define LNEPS 1e-6f
#define FFN_CHUNK 5440       // NTOK/8; 5440*1024 == NTOK*128 (reuses aw buffer)

// ---------------- block reduction (256 threads = 4 waves) ----------------
__device__ __forceinline__ float block_reduce_sum(float v, float* sbuf) {
#pragma unroll
  for (int off = 32; off > 0; off >>= 1) v += __shfl_down(v, off, 64);
  int lane = threadIdx.x & 63;
  int w = threadIdx.x >> 6;
  if (lane == 0) sbuf[w] = v;
  __syncthreads();
  if (threadIdx.x == 0) sbuf[4] = sbuf[0] + sbuf[1] + sbuf[2] + sbuf[3];
  __syncthreads();
  return sbuf[4];
}

// ---------------- plain layernorm: o = LN(in)*g + beta ----------------
__global__ __launch_bounds__(256) void ln_k(const float* __restrict__ in,
                                            const float* __restrict__ g,
                                            const float* __restrict__ beta,
                                            float* __restrict__ o) {
  __shared__ float sbuf[8];
  int t = blockIdx.x;
  int c = threadIdx.x;
  size_t base = (size_t)t * DMODEL + c;
  float v = in[base];
  float s = block_reduce_sum(v, sbuf);
  float mu = s * (1.0f / DMODEL);
  float d = v - mu;
  float s2 = block_reduce_sum(d * d, sbuf);
  float rs = rsqrtf(s2 * (1.0f / DMODEL) + LNEPS);
  o[base] = d * rs * g[c] + beta[c];
}

// ---------------- tiled f32 GEMM: C = (A[+A2]) @ W + bias [+res] ----------
// BM=BN=64, BK=16, 256 threads, 4x4 microtile. All dims divisible.
template <bool RELU, bool ADDRES, bool ADDA2>
__global__ __launch_bounds__(256) void gemm_f32(const float* __restrict__ A,
                                                const float* __restrict__ A2,
                                                const float* __restrict__ W,
                                                const float* __restrict__ bias,
                                                const float* __restrict__ res,
                                                float* __restrict__ C,
                                                int M, int N, int K) {
  __shared__ float As[64][17];  // [m][k], +1 pad
  __shared__ float Bs[16][64];  // [k][n]
  int tid = threadIdx.x;
  int tx = tid & 15, ty = tid >> 4;
  int arow = tid >> 2, acol = (tid & 3) << 2;
  int brow = tid >> 4, bcol = (tid & 15) << 2;
  int m0 = blockIdx.x * 64, n0 = blockIdx.y * 64;
  const float* Ap = A + (size_t)(m0 + arow) * K + acol;
  const float* A2p = ADDA2 ? (A2 + (size_t)(m0 + arow) * K + acol) : nullptr;
  const float* Wp = W + (size_t)brow * N + n0 + bcol;
  float acc[4][4] = {};
  for (int k0 = 0; k0 < K; k0 += 16) {
    float4 av = *(const float4*)(Ap + k0);
    if (ADDA2) {
      float4 av2 = *(const float4*)(A2p + k0);
      av.x += av2.x; av.y += av2.y; av.z += av2.z; av.w += av2.w;
    }
    As[arow][acol + 0] = av.x;
    As[arow][acol + 1] = av.y;
    As[arow][acol + 2] = av.z;
    As[arow][acol + 3] = av.w;
    float4 wv = *(const float4*)(Wp + (size_t)k0 * N);
    *(float4*)(&Bs[brow][bcol]) = wv;
    __syncthreads();
#pragma unroll
    for (int kk = 0; kk < 16; kk++) {
      float a[4], b[4];
#pragma unroll
      for (int i = 0; i < 4; i++) a[i] = As[ty * 4 + i][kk];
#pragma unroll
      for (int j = 0; j < 4; j++) b[j] = Bs[kk][tx * 4 + j];
#pragma unroll
      for (int i = 0; i < 4; i++)
#pragma unroll
        for (int j = 0; j < 4; j++) acc[i][j] = fmaf(a[i], b[j], acc[i][j]);
    }
    __syncthreads();
  }
  int row0 = m0 + ty * 4, col0 = n0 + tx * 4;
#pragma unroll
  for (int i = 0; i < 4; i++) {
#pragma unroll
    for (int j = 0; j < 4; j++) {
      float cv = acc[i][j] + bias[col0 + j];
      if (RELU) cv = fmaxf(cv, 0.0f);
      if (ADDRES) cv += res[(size_t)(row0 + i) * N + col0 + j];
      C[(size_t)(row0 + i) * N + col0 + j] = cv;
    }
  }
}

// ---------------- softmax over last-16 (per b,q,h row) ----------------
__global__ __launch_bounds__(256) void softmax16(float* __restrict__ E) {
  int r = blockIdx.x * 256 + threadIdx.x;
  if (r >= NTOK * NHEAD) return;
  float* p = E + (size_t)r * 16;
  float vals[16];
  float m = -1e30f;
#pragma unroll
  for (int i = 0; i < 16; i++) {
    vals[i] = p[i];
    m = fmaxf(m, vals[i]);
  }
  float s = 0.f;
#pragma unroll
  for (int i = 0; i < 16; i++) {
    vals[i] = expf(vals[i] - m);
    s += vals[i];
  }
  float inv = 1.0f / s;
#pragma unroll
  for (int i = 0; i < 16; i++) p[i] = vals[i] * inv;
}

// ---------------- deformable bilinear sampling ----------------
// One block per (b,q); thread = head*32 + channel. 4 corner loads are 128B
// coalesced across channels. val layout: (B, LQ, NH, DH).
__global__ __launch_bounds__(256) void deform_sample(
    const float* __restrict__ val, const float* __restrict__ off,
    const float* __restrict__ aw, const float* __restrict__ refp,
    float* __restrict__ out) {
  const int HW_[4] = {128, 64, 32, 16};          // square levels
  const int LSI_[4] = {0, 16384, 20480, 21504};  // level start index
  int bq = blockIdx.x;
  int h = threadIdx.x >> 5;
  int d = threadIdx.x & 31;
  int b = bq / LQTOK;
  const float* offp = off + (size_t)bq * 256;
  const float* awp = aw + (size_t)bq * 128 + h * 16;
  const float* rp = refp + (size_t)bq * (NLEVEL * 2);
  float acc = 0.f;
#pragma unroll
  for (int l = 0; l < NLEVEL; l++) {
    int HW = HW_[l];
    float rx = rp[l * 2 + 0];
    float ry = rp[l * 2 + 1];
    const float* vbase =
        val + ((size_t)(b * LQTOK + LSI_[l])) * DMODEL + h * DHEAD + d;
#pragma unroll
    for (int p = 0; p < NPOINT; p++) {
      int oi = ((h * NLEVEL + l) * NPOINT + p) * 2;
      float x = fmaf(rx, (float)HW, offp[oi + 0]) - 0.5f;
      float y = fmaf(ry, (float)HW, offp[oi + 1]) - 0.5f;
      float xf = floorf(x), yf = floorf(y);
      int x0 = (int)xf, y0 = (int)yf;
      float lx = x - xf, ly = y - yf;
      bool xin0 = (x0 >= 0) && (x0 < HW);
      bool xin1 = (x0 + 1 >= 0) && (x0 + 1 < HW);
      bool yin0 = (y0 >= 0) && (y0 < HW);
      bool yin1 = (y0 + 1 >= 0) && (y0 + 1 < HW);
      float v00 = 0.f, v10 = 0.f, v01 = 0.f, v11 = 0.f;
      if (xin0 && yin0) v00 = vbase[(size_t)(y0 * HW + x0) * DMODEL];
      if (xin1 && yin0) v10 = vbase[(size_t)(y0 * HW + x0 + 1) * DMODEL];
      if (xin0 && yin1) v01 = vbase[(size_t)((y0 + 1) * HW + x0) * DMODEL];
      if (xin1 && yin1) v11 = vbase[(size_t)((y0 + 1) * HW + x0 + 1) * DMODEL];
      float bil = (1.f - lx) * (1.f - ly) * v00 + lx * (1.f - ly) * v10 +
                  (1.f - lx) * ly * v01 + lx * ly * v11;
      acc = fmaf(awp[l * NPOINT + p], bil, acc);
    }
  }
  out[(size_t)bq * DMODEL + threadIdx.x] = acc;
}

// ---------------- launch ----------------
extern "C" void kernel_launch(void* const* d_in, const int* in_sizes, int n_in,
                              void* d_out, int out_size, void* d_ws,
                              size_t ws_size, hipStream_t stream) {
  const float* src    = (const float*)d_in[0];
  const float* pos    = (const float*)d_in[1];
  const float* refp   = (const float*)d_in[2];
  // d_in[3]=spatial_shapes, d_in[4]=level_start_index: compile-time constants
  const float* g1     = (const float*)d_in[5];
  const float* beta1  = (const float*)d_in[6];
  const float* w_off  = (const float*)d_in[7];
  const float* b_off  = (const float*)d_in[8];
  const float* w_attn = (const float*)d_in[9];
  const float* b_attn = (const float*)d_in[10];
  const float* w_val  = (const float*)d_in[11];
  const float* b_val  = (const float*)d_in[12];
  const float* w_out  = (const float*)d_in[13];
  const float* b_out  = (const float*)d_in[14];
  const float* g2     = (const float*)d_in[15];
  const float* beta2  = (const float*)d_in[16];
  const float* w_fc1  = (const float*)d_in[17];
  const float* b_fc1  = (const float*)d_in[18];
  const float* w_fc2  = (const float*)d_in[19];
  const float* b_fc2  = (const float*)d_in[20];
  float* out = (float*)d_out;

  // Workspace (floats): A,B,C = NT*256 each, D = NT*128.
  // Total = 896*NTOK floats = 148.75 MiB.
  float* ws = (float*)d_ws;
  const size_t NT = (size_t)NTOK;
  float* bufA = ws;               // x            -> sampled
  float* bufB = bufA + NT * 256;  // val          -> src2
  float* bufC = bufB + NT * 256;  // off          -> y
  float* bufD = bufC + NT * 256;  // attn logits/aw -> ffn hidden chunks

  const int MT = NTOK / 64;  // 680 row tiles

  // 1. x = LN(src)
  ln_k<<<NTOK, 256, 0, stream>>>(src, g1, beta1, bufA);
  // 2. val = x @ w_val + b_val
  gemm_f32<false, false, false><<<dim3(MT, 4), 256, 0, stream>>>(
      bufA, nullptr, w_val, b_val, nullptr, bufB, NTOK, 256, 256);
  // 3. off = (x+pos) @ w_off + b_off    (q fused into A-load)
  gemm_f32<false, false, true><<<dim3(MT, 4), 256, 0, stream>>>(
      bufA, pos, w_off, b_off, nullptr, bufC, NTOK, 256, 256);
  // 4. logits = (x+pos) @ w_attn + b_attn
  gemm_f32<false, false, true><<<dim3(MT, 2), 256, 0, stream>>>(
      bufA, pos, w_attn, b_attn, nullptr, bufD, NTOK, 128, 256);
  // 5. softmax over 16 (per b,q,h)
  softmax16<<<(NTOK * NHEAD + 255) / 256, 256, 0, stream>>>(bufD);
  // 6. deformable sampling -> bufA (x dead)
  deform_sample<<<NTOK, 256, 0, stream>>>(bufB, bufC, bufD, refp, bufA);
  // 7. src2 = sampled @ w_out + b_out + src   (residual fused; val dead)
  gemm_f32<false, true, false><<<dim3(MT, 4), 256, 0, stream>>>(
      bufA, nullptr, w_out, b_out, src, bufB, NTOK, 256, 256);
  // 8. y = LN(src2)   (off dead)
  ln_k<<<NTOK, 256, 0, stream>>>(bufB, g2, beta2, bufC);
  // 9/10. FFN in 8 row chunks; hidden (5440x1024) reuses bufD exactly.
  for (int c = 0; c < 8; c++) {
    size_t ro = (size_t)c * FFN_CHUNK;
    gemm_f32<true, false, false><<<dim3(FFN_CHUNK / 64, 16), 256, 0, stream>>>(
        bufC + ro * 256, nullptr, w_fc1, b_fc1, nullptr, bufD,
        FFN_CHUNK, 1024, 256);
    gemm_f32<false, true, false><<<dim3(FFN_CHUNK / 64, 4), 256, 0, stream>>>(
        bufD, nullptr, w_fc2, b_fc2, bufB + ro * 256, out + ro * 256,
        FFN_CHUNK, 256, 1024);
  }
}

// Round 3
// 893.109 us; speedup vs baseline: 2.1937x; 2.1937x over previous
//
#include <hip/hip_runtime.h>

// MSDeformAttn encoder layer — bf16 MFMA GEMMs + branchless sampling.
#define DMODEL 256
#define NHEAD 8
#define NPOINT 4
#define NLEVEL 4
#define DHEAD 32
#define MLPD 1024
#define BSZ 2
#define LQTOK 21760
#define NTOK (BSZ * LQTOK)  // 43520
#define LNEPS 1e-6f
#define FFN_CHUNK 8704      // NTOK/5, divisible by 128

typedef __attribute__((ext_vector_type(8))) short short8;
typedef __attribute__((ext_vector_type(4))) float f32x4;

__device__ __forceinline__ float bf2f(unsigned short u) {
  unsigned int i = ((unsigned int)u) << 16;
  return __builtin_bit_cast(float, i);
}
__device__ __forceinline__ unsigned short f2bf(float f) {
  unsigned int i = __builtin_bit_cast(unsigned int, f);
  i += 0x7fff + ((i >> 16) & 1);  // round-to-nearest-even
  return (unsigned short)(i >> 16);
}

// ---------------- block reduction (256 threads = 4 waves) ----------------
__device__ __forceinline__ float block_reduce_sum(float v, float* sbuf) {
#pragma unroll
  for (int off = 32; off > 0; off >>= 1) v += __shfl_down(v, off, 64);
  int lane = threadIdx.x & 63;
  int w = threadIdx.x >> 6;
  if (lane == 0) sbuf[w] = v;
  __syncthreads();
  if (threadIdx.x == 0) sbuf[4] = sbuf[0] + sbuf[1] + sbuf[2] + sbuf[3];
  __syncthreads();
  return sbuf[4];
}

// ---------------- layernorm: o_bf16 = LN(in)*g + beta ----------------
__global__ __launch_bounds__(256) void ln_bf16(const float* __restrict__ in,
                                               const float* __restrict__ g,
                                               const float* __restrict__ beta,
                                               unsigned short* __restrict__ o) {
  __shared__ float sbuf[8];
  int t = blockIdx.x;
  int c = threadIdx.x;
  size_t base = (size_t)t * DMODEL + c;
  float v = in[base];
  float s = block_reduce_sum(v, sbuf);
  float mu = s * (1.0f / DMODEL);
  float d = v - mu;
  float s2 = block_reduce_sum(d * d, sbuf);
  float rs = rsqrtf(s2 * (1.0f / DMODEL) + LNEPS);
  o[base] = f2bf(d * rs * g[c] + beta[c]);
}

// ---------------- transpose + cast: Wt[n][k] = bf16(W[k][n]) ----------------
__global__ __launch_bounds__(256) void transpose_bf16(const float* __restrict__ W,
                                                      unsigned short* __restrict__ Wt,
                                                      int K, int N) {
  __shared__ float tile[32][33];
  int k0 = blockIdx.x * 32, n0 = blockIdx.y * 32;
  int tx = threadIdx.x & 31, ty = threadIdx.x >> 5;  // 32 x 8
  for (int i = ty; i < 32; i += 8) tile[i][tx] = W[(size_t)(k0 + i) * N + n0 + tx];
  __syncthreads();
  for (int i = ty; i < 32; i += 8)
    Wt[(size_t)(n0 + i) * K + k0 + tx] = f2bf(tile[tx][i]);
}

// ---------------- bf16 MFMA GEMM: C = (A[+pos]) @ Wt^T + bias [...] --------
// Tile 128x128, BK=32, 256 threads = 4 waves (2x2 of 64x64), 4x4 MFMA
// 16x16x32 per wave. A: bf16 [M][K]. Wt: bf16 [N][K]. OMODE: 0=f32,
// 1=bf16, 2=bf16+relu, 3=f32+res.
template <bool ADDPOS, int OMODE>
__global__ __launch_bounds__(256) void gemm_mfma(
    const unsigned short* __restrict__ A, const float* __restrict__ pos,
    const unsigned short* __restrict__ Wt, const float* __restrict__ bias,
    const float* __restrict__ res, void* __restrict__ Cout, int M, int N,
    int K) {
  // pitch 40 bf16 (80 B): fragment/staging b128 accesses alias <=2-way (free)
  __shared__ __attribute__((aligned(16))) unsigned short As[128 * 40];
  __shared__ __attribute__((aligned(16))) unsigned short Bs[128 * 40];
  const int tid = threadIdx.x;
  const int m0 = blockIdx.x * 128, n0 = blockIdx.y * 128;
  const int wave = tid >> 6, lane = tid & 63;
  const int wm = (wave & 1) * 64, wn = (wave >> 1) * 64;
  const int lr = lane & 15, quad = lane >> 4;
  f32x4 acc[4][4] = {};
  for (int k0 = 0; k0 < K; k0 += 32) {
    __syncthreads();
#pragma unroll
    for (int i = 0; i < 2; i++) {
      int s = tid + 256 * i;
      int row = s >> 2, c8 = (s & 3) * 8;
      const unsigned short* ga = A + (size_t)(m0 + row) * K + k0 + c8;
      if (ADDPOS) {
        const float* gp = pos + (size_t)(m0 + row) * K + k0 + c8;
        float4 p0 = *(const float4*)gp;
        float4 p1 = *(const float4*)(gp + 4);
        short8 xv = *(const short8*)ga;
        short8 ov;
        ov[0] = (short)f2bf(bf2f((unsigned short)xv[0]) + p0.x);
        ov[1] = (short)f2bf(bf2f((unsigned short)xv[1]) + p0.y);
        ov[2] = (short)f2bf(bf2f((unsigned short)xv[2]) + p0.z);
        ov[3] = (short)f2bf(bf2f((unsigned short)xv[3]) + p0.w);
        ov[4] = (short)f2bf(bf2f((unsigned short)xv[4]) + p1.x);
        ov[5] = (short)f2bf(bf2f((unsigned short)xv[5]) + p1.y);
        ov[6] = (short)f2bf(bf2f((unsigned short)xv[6]) + p1.z);
        ov[7] = (short)f2bf(bf2f((unsigned short)xv[7]) + p1.w);
        *(short8*)(&As[row * 40 + c8]) = ov;
      } else {
        *(short8*)(&As[row * 40 + c8]) = *(const short8*)ga;
      }
      const unsigned short* gb = Wt + (size_t)(n0 + row) * K + k0 + c8;
      *(short8*)(&Bs[row * 40 + c8]) = *(const short8*)gb;
    }
    __syncthreads();
    short8 af[4], bfr[4];
#pragma unroll
    for (int i = 0; i < 4; i++)
      af[i] = *(const short8*)(&As[(wm + i * 16 + lr) * 40 + quad * 8]);
#pragma unroll
    for (int j = 0; j < 4; j++)
      bfr[j] = *(const short8*)(&Bs[(wn + j * 16 + lr) * 40 + quad * 8]);
#pragma unroll
    for (int i = 0; i < 4; i++)
#pragma unroll
      for (int j = 0; j < 4; j++)
        acc[i][j] = __builtin_amdgcn_mfma_f32_16x16x32_bf16(af[i], bfr[j],
                                                            acc[i][j], 0, 0, 0);
  }
  // epilogue: C/D layout col=lane&15, row=quad*4+reg
#pragma unroll
  for (int i = 0; i < 4; i++) {
    int rbase = m0 + wm + i * 16 + quad * 4;
#pragma unroll
    for (int j = 0; j < 4; j++) {
      int col = n0 + wn + j * 16 + lr;
      float bv = bias[col];
#pragma unroll
      for (int r = 0; r < 4; r++) {
        size_t idx = (size_t)(rbase + r) * N + col;
        float v = acc[i][j][r] + bv;
        if (OMODE == 2) v = fmaxf(v, 0.0f);
        if (OMODE == 3) v += res[idx];
        if (OMODE == 0 || OMODE == 3)
          ((float*)Cout)[idx] = v;
        else
          ((unsigned short*)Cout)[idx] = f2bf(v);
      }
    }
  }
}

// ---------------- softmax over last-16 (per b,q,h row), f32 in place -------
__global__ __launch_bounds__(256) void softmax16(float* __restrict__ E) {
  int r = blockIdx.x * 256 + threadIdx.x;
  if (r >= NTOK * NHEAD) return;
  float* p = E + (size_t)r * 16;
  float vals[16];
  float m = -1e30f;
#pragma unroll
  for (int i = 0; i < 16; i++) {
    vals[i] = p[i];
    m = fmaxf(m, vals[i]);
  }
  float s = 0.f;
#pragma unroll
  for (int i = 0; i < 16; i++) {
    vals[i] = expf(vals[i] - m);
    s += vals[i];
  }
  float inv = 1.0f / s;
#pragma unroll
  for (int i = 0; i < 16; i++) p[i] = vals[i] * inv;
}

// ---------------- deformable bilinear sampling (branchless, bf16) ----------
// One block per (b,q); thread = head*32 + channel. Corner loads coalesced
// 64B across the 32 channels of a head. val layout (B, LQ, NH, DH) bf16.
__global__ __launch_bounds__(256) void deform_sample(
    const unsigned short* __restrict__ val, const unsigned short* __restrict__ off,
    const float* __restrict__ aw, const float* __restrict__ refp,
    unsigned short* __restrict__ out) {
  const int HW_[4] = {128, 64, 32, 16};
  const int LSI_[4] = {0, 16384, 20480, 21504};
  int bq = blockIdx.x;
  int h = threadIdx.x >> 5;
  int d = threadIdx.x & 31;
  int b = bq / LQTOK;
  const unsigned short* offp = off + (size_t)bq * 256;
  const float* awp = aw + (size_t)bq * 128 + h * 16;
  const float* rp = refp + (size_t)bq * (NLEVEL * 2);
  float acc = 0.f;
#pragma unroll
  for (int l = 0; l < NLEVEL; l++) {
    int HW = HW_[l];
    float rx = rp[l * 2 + 0];
    float ry = rp[l * 2 + 1];
    const unsigned short* vbase =
        val + ((size_t)(b * LQTOK + LSI_[l])) * DMODEL + h * DHEAD + d;
#pragma unroll
    for (int p = 0; p < NPOINT; p++) {
      int oi = ((h * NLEVEL + l) * NPOINT + p) * 2;
      float x = fmaf(rx, (float)HW, bf2f(offp[oi + 0])) - 0.5f;
      float y = fmaf(ry, (float)HW, bf2f(offp[oi + 1])) - 0.5f;
      float xf = floorf(x), yf = floorf(y);
      int x0 = (int)xf, y0 = (int)yf;
      float lx = x - xf, ly = y - yf;
      // clamped indices + masked weights (branchless)
      int x0c = min(max(x0, 0), HW - 1);
      int x1c = min(max(x0 + 1, 0), HW - 1);
      int y0c = min(max(y0, 0), HW - 1);
      int y1c = min(max(y0 + 1, 0), HW - 1);
      float mx0 = (x0 >= 0 && x0 < HW) ? 1.f : 0.f;
      float mx1 = (x0 + 1 >= 0 && x0 + 1 < HW) ? 1.f : 0.f;
      float my0 = (y0 >= 0 && y0 < HW) ? 1.f : 0.f;
      float my1 = (y0 + 1 >= 0 && y0 + 1 < HW) ? 1.f : 0.f;
      float w00 = (1.f - lx) * (1.f - ly) * mx0 * my0;
      float w10 = lx * (1.f - ly) * mx1 * my0;
      float w01 = (1.f - lx) * ly * mx0 * my1;
      float w11 = lx * ly * mx1 * my1;
      float v00 = bf2f(vbase[(size_t)(y0c * HW + x0c) * DMODEL]);
      float v10 = bf2f(vbase[(size_t)(y0c * HW + x1c) * DMODEL]);
      float v01 = bf2f(vbase[(size_t)(y1c * HW + x0c) * DMODEL]);
      float v11 = bf2f(vbase[(size_t)(y1c * HW + x1c) * DMODEL]);
      float bil = w00 * v00 + w10 * v10 + w01 * v01 + w11 * v11;
      acc = fmaf(awp[l * NPOINT + p], bil, acc);
    }
  }
  out[(size_t)bq * DMODEL + threadIdx.x] = f2bf(acc);
}

// ---------------- launch ----------------
extern "C" void kernel_launch(void* const* d_in, const int* in_sizes, int n_in,
                              void* d_out, int out_size, void* d_ws,
                              size_t ws_size, hipStream_t stream) {
  const float* src    = (const float*)d_in[0];
  const float* pos    = (const float*)d_in[1];
  const float* refp   = (const float*)d_in[2];
  const float* g1     = (const float*)d_in[5];
  const float* beta1  = (const float*)d_in[6];
  const float* w_off  = (const float*)d_in[7];
  const float* b_off  = (const float*)d_in[8];
  const float* w_attn = (const float*)d_in[9];
  const float* b_attn = (const float*)d_in[10];
  const float* w_val  = (const float*)d_in[11];
  const float* b_val  = (const float*)d_in[12];
  const float* w_out  = (const float*)d_in[13];
  const float* b_out  = (const float*)d_in[14];
  const float* g2     = (const float*)d_in[15];
  const float* beta2  = (const float*)d_in[16];
  const float* w_fc1  = (const float*)d_in[17];
  const float* b_fc1  = (const float*)d_in[18];
  const float* w_fc2  = (const float*)d_in[19];
  const float* b_fc2  = (const float*)d_in[20];
  float* out = (float*)d_out;

  // Workspace: 135.2 MB total.
  const size_t NT = (size_t)NTOK;
  unsigned short* b1 = (unsigned short*)d_ws;  // x bf16 -> sampled bf16
  unsigned short* b2 = b1 + NT * 256;          // val bf16
  unsigned short* b3 = b2 + NT * 256;          // off bf16 -> y bf16
  float* b4 = (float*)(b3 + NT * 256);         // aw f32 -> ffn hidden bf16
  float* b5 = b4 + NT * 128;                   // src2 f32
  unsigned short* wvalT  = (unsigned short*)(b5 + NT * 256);  // [256][256]
  unsigned short* woffT  = wvalT + 256 * 256;                 // [256][256]
  unsigned short* wattnT = woffT + 256 * 256;                 // [128][256]
  unsigned short* woutT  = wattnT + 128 * 256;                // [256][256]
  unsigned short* wfc1T  = woutT + 256 * 256;                 // [1024][256]
  unsigned short* wfc2T  = wfc1T + 1024 * 256;                // [256][1024]

  // 0. weight transposes (f32 -> bf16, [K][N] -> [N][K])
  transpose_bf16<<<dim3(8, 8), 256, 0, stream>>>(w_val, wvalT, 256, 256);
  transpose_bf16<<<dim3(8, 8), 256, 0, stream>>>(w_off, woffT, 256, 256);
  transpose_bf16<<<dim3(8, 4), 256, 0, stream>>>(w_attn, wattnT, 256, 128);
  transpose_bf16<<<dim3(8, 8), 256, 0, stream>>>(w_out, woutT, 256, 256);
  transpose_bf16<<<dim3(8, 32), 256, 0, stream>>>(w_fc1, wfc1T, 256, 1024);
  transpose_bf16<<<dim3(32, 8), 256, 0, stream>>>(w_fc2, wfc2T, 1024, 256);

  const int MT = NTOK / 128;  // 340

  // 1. x = LN(src) -> bf16
  ln_bf16<<<NTOK, 256, 0, stream>>>(src, g1, beta1, b1);
  // 2. val = x @ w_val + b_val -> bf16
  gemm_mfma<false, 1><<<dim3(MT, 2), 256, 0, stream>>>(
      b1, nullptr, wvalT, b_val, nullptr, b2, NTOK, 256, 256);
  // 3. off = (x+pos) @ w_off + b_off -> bf16
  gemm_mfma<true, 1><<<dim3(MT, 2), 256, 0, stream>>>(
      b1, pos, woffT, b_off, nullptr, b3, NTOK, 256, 256);
  // 4. logits = (x+pos) @ w_attn + b_attn -> f32
  gemm_mfma<true, 0><<<dim3(MT, 1), 256, 0, stream>>>(
      b1, pos, wattnT, b_attn, nullptr, b4, NTOK, 128, 256);
  // 5. softmax over 16
  softmax16<<<(NTOK * NHEAD + 255) / 256, 256, 0, stream>>>(b4);
  // 6. sampling -> b1 (x dead)
  deform_sample<<<NTOK, 256, 0, stream>>>(b2, b3, b4, refp, b1);
  // 7. src2 = sampled @ w_out + b_out + src -> f32
  gemm_mfma<false, 3><<<dim3(MT, 2), 256, 0, stream>>>(
      b1, nullptr, woutT, b_out, src, b5, NTOK, 256, 256);
  // 8. y = LN(src2) -> bf16 (off dead)
  ln_bf16<<<NTOK, 256, 0, stream>>>(b5, g2, beta2, b3);
  // 9/10. FFN in 5 chunks; hidden bf16 reuses b4 (aw dead).
  unsigned short* hid = (unsigned short*)b4;
  for (int c = 0; c < 5; c++) {
    size_t ro = (size_t)c * FFN_CHUNK;
    gemm_mfma<false, 2><<<dim3(FFN_CHUNK / 128, 8), 256, 0, stream>>>(
        b3 + ro * 256, nullptr, wfc1T, b_fc1, nullptr, hid,
        FFN_CHUNK, 1024, 256);
    gemm_mfma<false, 3><<<dim3(FFN_CHUNK / 128, 2), 256, 0, stream>>>(
        hid, nullptr, wfc2T, b_fc2, b5 + ro * 256, out + ro * 256,
        FFN_CHUNK, 256, 1024);
  }
}

// Round 4
// 858.630 us; speedup vs baseline: 2.2817x; 1.0402x over previous
//
#include <hip/hip_runtime.h>

// MSDeformAttn encoder layer — bf16 MFMA GEMMs (global_load_lds staging) +
// two-phase deformable sampling (coordinate math deduplicated via LDS).
#define DMODEL 256
#define NHEAD 8
#define NPOINT 4
#define NLEVEL 4
#define DHEAD 32
#define MLPD 1024
#define BSZ 2
#define LQTOK 21760
#define NTOK (BSZ * LQTOK)  // 43520
#define LNEPS 1e-6f
#define FFN_CHUNK 8704      // NTOK/5, divisible by 128

typedef __attribute__((ext_vector_type(8))) short short8;
typedef __attribute__((ext_vector_type(4))) float f32x4;

__device__ __forceinline__ float bf2f(unsigned short u) {
  unsigned int i = ((unsigned int)u) << 16;
  return __builtin_bit_cast(float, i);
}
__device__ __forceinline__ unsigned short f2bf(float f) {
  unsigned int i = __builtin_bit_cast(unsigned int, f);
  i += 0x7fff + ((i >> 16) & 1);  // round-to-nearest-even
  return (unsigned short)(i >> 16);
}

// async global->LDS, 16B per lane; lds dest = wave-uniform base + lane*16
__device__ __forceinline__ void gload_lds16(const unsigned short* g,
                                            unsigned short* lds) {
  __builtin_amdgcn_global_load_lds(
      (const __attribute__((address_space(1))) unsigned int*)g,
      (__attribute__((address_space(3))) unsigned int*)lds, 16, 0, 0);
}

// ---------------- block reduction (256 threads = 4 waves) ----------------
__device__ __forceinline__ float block_reduce_sum(float v, float* sbuf) {
#pragma unroll
  for (int off = 32; off > 0; off >>= 1) v += __shfl_down(v, off, 64);
  int lane = threadIdx.x & 63;
  int w = threadIdx.x >> 6;
  if (lane == 0) sbuf[w] = v;
  __syncthreads();
  if (threadIdx.x == 0) sbuf[4] = sbuf[0] + sbuf[1] + sbuf[2] + sbuf[3];
  __syncthreads();
  return sbuf[4];
}

// ---------------- layernorm: o_bf16 = LN(in)*g + beta ----------------
__global__ __launch_bounds__(256) void ln_bf16(const float* __restrict__ in,
                                               const float* __restrict__ g,
                                               const float* __restrict__ beta,
                                               unsigned short* __restrict__ o) {
  __shared__ float sbuf[8];
  int t = blockIdx.x;
  int c = threadIdx.x;
  size_t base = (size_t)t * DMODEL + c;
  float v = in[base];
  float s = block_reduce_sum(v, sbuf);
  float mu = s * (1.0f / DMODEL);
  float d = v - mu;
  float s2 = block_reduce_sum(d * d, sbuf);
  float rs = rsqrtf(s2 * (1.0f / DMODEL) + LNEPS);
  o[base] = f2bf(d * rs * g[c] + beta[c]);
}

// ---------------- transpose + cast: Wt[n][k] = bf16(W[k][n]) ----------------
__global__ __launch_bounds__(256) void transpose_bf16(const float* __restrict__ W,
                                                      unsigned short* __restrict__ Wt,
                                                      int K, int N) {
  __shared__ float tile[32][33];
  int k0 = blockIdx.x * 32, n0 = blockIdx.y * 32;
  int tx = threadIdx.x & 31, ty = threadIdx.x >> 5;  // 32 x 8
  for (int i = ty; i < 32; i += 8) tile[i][tx] = W[(size_t)(k0 + i) * N + n0 + tx];
  __syncthreads();
  for (int i = ty; i < 32; i += 8)
    Wt[(size_t)(n0 + i) * K + k0 + tx] = f2bf(tile[tx][i]);
}

// ---------------- bf16 MFMA GEMM: C = (A[+pos]) @ Wt^T + bias [...] --------
// Tile 128x128, BK=32, 256 threads = 4 waves (2x2 of 64x64), 4x4 MFMA
// 16x16x32 per wave. A: bf16 [M][K]. Wt: bf16 [N][K]. Unpadded pitch-32 LDS
// (m97 layout — required by global_load_lds). OMODE: 0=f32, 1=bf16,
// 2=bf16+relu, 3=f32+res.
template <bool ADDPOS, int OMODE>
__global__ __launch_bounds__(256) void gemm_mfma(
    const unsigned short* __restrict__ A, const float* __restrict__ pos,
    const unsigned short* __restrict__ Wt, const float* __restrict__ bias,
    const float* __restrict__ res, void* __restrict__ Cout, int M, int N,
    int K) {
  __shared__ __attribute__((aligned(16))) unsigned short As[128 * 32];
  __shared__ __attribute__((aligned(16))) unsigned short Bs[128 * 32];
  const int tid = threadIdx.x;
  const int m0 = blockIdx.x * 128, n0 = blockIdx.y * 128;
  const int wave = tid >> 6, lane = tid & 63;
  const int wm = (wave & 1) * 64, wn = (wave >> 1) * 64;
  const int lr = lane & 15, quad = lane >> 4;
  f32x4 acc[4][4] = {};
  for (int k0 = 0; k0 < K; k0 += 32) {
    __syncthreads();
    // B tile: direct-to-LDS. chunk c = r*256+tid; row=c>>2, col8=(c&3)*8;
    // lds short-offset = 8*c (contiguous per wave: base + lane*16B).
#pragma unroll
    for (int r = 0; r < 2; r++) {
      int c = r * 256 + tid;
      int row = c >> 2, col8 = (c & 3) * 8;
      gload_lds16(Wt + (size_t)(n0 + row) * K + k0 + col8,
                  &Bs[(r * 256 + wave * 64) * 8]);
    }
    if (!ADDPOS) {
#pragma unroll
      for (int r = 0; r < 2; r++) {
        int c = r * 256 + tid;
        int row = c >> 2, col8 = (c & 3) * 8;
        gload_lds16(A + (size_t)(m0 + row) * K + k0 + col8,
                    &As[(r * 256 + wave * 64) * 8]);
      }
    } else {
#pragma unroll
      for (int r = 0; r < 2; r++) {
        int s = tid + 256 * r;
        int row = s >> 2, c8 = (s & 3) * 8;
        const unsigned short* ga = A + (size_t)(m0 + row) * K + k0 + c8;
        const float* gp = pos + (size_t)(m0 + row) * K + k0 + c8;
        float4 p0 = *(const float4*)gp;
        float4 p1 = *(const float4*)(gp + 4);
        short8 xv = *(const short8*)ga;
        short8 ov;
        ov[0] = (short)f2bf(bf2f((unsigned short)xv[0]) + p0.x);
        ov[1] = (short)f2bf(bf2f((unsigned short)xv[1]) + p0.y);
        ov[2] = (short)f2bf(bf2f((unsigned short)xv[2]) + p0.z);
        ov[3] = (short)f2bf(bf2f((unsigned short)xv[3]) + p0.w);
        ov[4] = (short)f2bf(bf2f((unsigned short)xv[4]) + p1.x);
        ov[5] = (short)f2bf(bf2f((unsigned short)xv[5]) + p1.y);
        ov[6] = (short)f2bf(bf2f((unsigned short)xv[6]) + p1.z);
        ov[7] = (short)f2bf(bf2f((unsigned short)xv[7]) + p1.w);
        *(short8*)(&As[row * 32 + c8]) = ov;
      }
    }
    __syncthreads();
    short8 af[4], bfr[4];
#pragma unroll
    for (int i = 0; i < 4; i++)
      af[i] = *(const short8*)(&As[(wm + i * 16 + lr) * 32 + quad * 8]);
#pragma unroll
    for (int j = 0; j < 4; j++)
      bfr[j] = *(const short8*)(&Bs[(wn + j * 16 + lr) * 32 + quad * 8]);
#pragma unroll
    for (int i = 0; i < 4; i++)
#pragma unroll
      for (int j = 0; j < 4; j++)
        acc[i][j] = __builtin_amdgcn_mfma_f32_16x16x32_bf16(af[i], bfr[j],
                                                            acc[i][j], 0, 0, 0);
  }
  // epilogue: C/D layout col=lane&15, row=quad*4+reg
#pragma unroll
  for (int i = 0; i < 4; i++) {
    int rbase = m0 + wm + i * 16 + quad * 4;
#pragma unroll
    for (int j = 0; j < 4; j++) {
      int col = n0 + wn + j * 16 + lr;
      float bv = bias[col];
#pragma unroll
      for (int r = 0; r < 4; r++) {
        size_t idx = (size_t)(rbase + r) * N + col;
        float v = acc[i][j][r] + bv;
        if (OMODE == 2) v = fmaxf(v, 0.0f);
        if (OMODE == 3) v += res[idx];
        if (OMODE == 0 || OMODE == 3)
          ((float*)Cout)[idx] = v;
        else
          ((unsigned short*)Cout)[idx] = f2bf(v);
      }
    }
  }
}

// ---------------- softmax over last-16 (per b,q,h row), f32 in place -------
__global__ __launch_bounds__(256) void softmax16(float* __restrict__ E) {
  int r = blockIdx.x * 256 + threadIdx.x;
  if (r >= NTOK * NHEAD) return;
  float* p = E + (size_t)r * 16;
  float vals[16];
  float m = -1e30f;
#pragma unroll
  for (int i = 0; i < 16; i++) {
    vals[i] = p[i];
    m = fmaxf(m, vals[i]);
  }
  float s = 0.f;
#pragma unroll
  for (int i = 0; i < 16; i++) {
    vals[i] = expf(vals[i] - m);
    s += vals[i];
  }
  float inv = 1.0f / s;
#pragma unroll
  for (int i = 0; i < 16; i++) p[i] = vals[i] * inv;
}

// ---------------- deformable sampling, two-phase ----------------
// Phase 1: threads 0..127, one per (h,l,p): compute 4 clamped flat element
// indices + 4 aw-prescaled masked bilinear weights -> LDS.
// Phase 2: thread = h*32+d: 16 points x (broadcast LDS read + 4 gathers +
// 4 fma). Gathers are 64B-coalesced across the 32 channels of a head.
__global__ __launch_bounds__(256) void deform_sample(
    const unsigned short* __restrict__ val, const unsigned short* __restrict__ off,
    const float* __restrict__ aw, const float* __restrict__ refp,
    unsigned short* __restrict__ out) {
  __shared__ __attribute__((aligned(16))) int sIdx[128][4];
  __shared__ __attribute__((aligned(16))) float sW[128][4];
  int bq = blockIdx.x;
  int b = bq / LQTOK;
  int t = threadIdx.x;
  if (t < 128) {
    const int HW_[4] = {128, 64, 32, 16};
    const int LSI_[4] = {0, 16384, 20480, 21504};
    int h = t >> 4, l = (t >> 2) & 3;
    int HW = HW_[l];
    float rx = refp[(size_t)bq * 8 + l * 2 + 0];
    float ry = refp[(size_t)bq * 8 + l * 2 + 1];
    // off col index = 2*t (layouts coincide: (h*NL+l)*NP+p == t)
    unsigned int ov = *(const unsigned int*)&off[(size_t)bq * 256 + 2 * t];
    float x = fmaf(rx, (float)HW, bf2f((unsigned short)(ov & 0xffff))) - 0.5f;
    float y = fmaf(ry, (float)HW, bf2f((unsigned short)(ov >> 16))) - 0.5f;
    float xf = floorf(x), yf = floorf(y);
    int x0 = (int)xf, y0 = (int)yf;
    float lx = x - xf, ly = y - yf;
    int x0c = min(max(x0, 0), HW - 1);
    int x1c = min(max(x0 + 1, 0), HW - 1);
    int y0c = min(max(y0, 0), HW - 1);
    int y1c = min(max(y0 + 1, 0), HW - 1);
    float mx0 = (x0 >= 0 && x0 < HW) ? 1.f : 0.f;
    float mx1 = (x0 + 1 >= 0 && x0 + 1 < HW) ? 1.f : 0.f;
    float my0 = (y0 >= 0 && y0 < HW) ? 1.f : 0.f;
    float my1 = (y0 + 1 >= 0 && y0 + 1 < HW) ? 1.f : 0.f;
    float a = aw[(size_t)bq * 128 + t];  // aw col == t as well
    int hb = h * DHEAD;
    sIdx[t][0] = (LSI_[l] + y0c * HW + x0c) * DMODEL + hb;
    sIdx[t][1] = (LSI_[l] + y0c * HW + x1c) * DMODEL + hb;
    sIdx[t][2] = (LSI_[l] + y1c * HW + x0c) * DMODEL + hb;
    sIdx[t][3] = (LSI_[l] + y1c * HW + x1c) * DMODEL + hb;
    sW[t][0] = (1.f - lx) * (1.f - ly) * mx0 * my0 * a;
    sW[t][1] = lx * (1.f - ly) * mx1 * my0 * a;
    sW[t][2] = (1.f - lx) * ly * mx0 * my1 * a;
    sW[t][3] = lx * ly * mx1 * my1 * a;
  }
  __syncthreads();
  int h = t >> 5, d = t & 31;
  const unsigned short* vb = val + (size_t)b * LQTOK * DMODEL + d;
  float acc = 0.f;
#pragma unroll
  for (int pt = 0; pt < 16; pt++) {
    int4 ix = *(const int4*)sIdx[h * 16 + pt];
    float4 w = *(const float4*)sW[h * 16 + pt];
    acc = fmaf(w.x, bf2f(vb[ix.x]), acc);
    acc = fmaf(w.y, bf2f(vb[ix.y]), acc);
    acc = fmaf(w.z, bf2f(vb[ix.z]), acc);
    acc = fmaf(w.w, bf2f(vb[ix.w]), acc);
  }
  out[(size_t)bq * DMODEL + t] = f2bf(acc);
}

// ---------------- launch ----------------
extern "C" void kernel_launch(void* const* d_in, const int* in_sizes, int n_in,
                              void* d_out, int out_size, void* d_ws,
                              size_t ws_size, hipStream_t stream) {
  const float* src    = (const float*)d_in[0];
  const float* pos    = (const float*)d_in[1];
  const float* refp   = (const float*)d_in[2];
  const float* g1     = (const float*)d_in[5];
  const float* beta1  = (const float*)d_in[6];
  const float* w_off  = (const float*)d_in[7];
  const float* b_off  = (const float*)d_in[8];
  const float* w_attn = (const float*)d_in[9];
  const float* b_attn = (const float*)d_in[10];
  const float* w_val  = (const float*)d_in[11];
  const float* b_val  = (const float*)d_in[12];
  const float* w_out  = (const float*)d_in[13];
  const float* b_out  = (const float*)d_in[14];
  const float* g2     = (const float*)d_in[15];
  const float* beta2  = (const float*)d_in[16];
  const float* w_fc1  = (const float*)d_in[17];
  const float* b_fc1  = (const float*)d_in[18];
  const float* w_fc2  = (const float*)d_in[19];
  const float* b_fc2  = (const float*)d_in[20];
  float* out = (float*)d_out;

  // Workspace: 135.2 MB total.
  const size_t NT = (size_t)NTOK;
  unsigned short* b1 = (unsigned short*)d_ws;  // x bf16 -> sampled bf16
  unsigned short* b2 = b1 + NT * 256;          // val bf16
  unsigned short* b3 = b2 + NT * 256;          // off bf16 -> y bf16
  float* b4 = (float*)(b3 + NT * 256);         // aw f32 -> ffn hidden bf16
  float* b5 = b4 + NT * 128;                   // src2 f32
  unsigned short* wvalT  = (unsigned short*)(b5 + NT * 256);  // [256][256]
  unsigned short* woffT  = wvalT + 256 * 256;                 // [256][256]
  unsigned short* wattnT = woffT + 256 * 256;                 // [128][256]
  unsigned short* woutT  = wattnT + 128 * 256;                // [256][256]
  unsigned short* wfc1T  = woutT + 256 * 256;                 // [1024][256]
  unsigned short* wfc2T  = wfc1T + 1024 * 256;                // [256][1024]

  // 0. weight transposes (f32 -> bf16, [K][N] -> [N][K])
  transpose_bf16<<<dim3(8, 8), 256, 0, stream>>>(w_val, wvalT, 256, 256);
  transpose_bf16<<<dim3(8, 8), 256, 0, stream>>>(w_off, woffT, 256, 256);
  transpose_bf16<<<dim3(8, 4), 256, 0, stream>>>(w_attn, wattnT, 256, 128);
  transpose_bf16<<<dim3(8, 8), 256, 0, stream>>>(w_out, woutT, 256, 256);
  transpose_bf16<<<dim3(8, 32), 256, 0, stream>>>(w_fc1, wfc1T, 256, 1024);
  transpose_bf16<<<dim3(32, 8), 256, 0, stream>>>(w_fc2, wfc2T, 1024, 256);

  const int MT = NTOK / 128;  // 340

  // 1. x = LN(src) -> bf16
  ln_bf16<<<NTOK, 256, 0, stream>>>(src, g1, beta1, b1);
  // 2. val = x @ w_val + b_val -> bf16
  gemm_mfma<false, 1><<<dim3(MT, 2), 256, 0, stream>>>(
      b1, nullptr, wvalT, b_val, nullptr, b2, NTOK, 256, 256);
  // 3. off = (x+pos) @ w_off + b_off -> bf16
  gemm_mfma<true, 1><<<dim3(MT, 2), 256, 0, stream>>>(
      b1, pos, woffT, b_off, nullptr, b3, NTOK, 256, 256);
  // 4. logits = (x+pos) @ w_attn + b_attn -> f32
  gemm_mfma<true, 0><<<dim3(MT, 1), 256, 0, stream>>>(
      b1, pos, wattnT, b_attn, nullptr, b4, NTOK, 128, 256);
  // 5. softmax over 16
  softmax16<<<(NTOK * NHEAD + 255) / 256, 256, 0, stream>>>(b4);
  // 6. sampling -> b1 (x dead)
  deform_sample<<<NTOK, 256, 0, stream>>>(b2, b3, b4, refp, b1);
  // 7. src2 = sampled @ w_out + b_out + src -> f32
  gemm_mfma<false, 3><<<dim3(MT, 2), 256, 0, stream>>>(
      b1, nullptr, woutT, b_out, src, b5, NTOK, 256, 256);
  // 8. y = LN(src2) -> bf16 (off dead)
  ln_bf16<<<NTOK, 256, 0, stream>>>(b5, g2, beta2, b3);
  // 9/10. FFN in 5 chunks; hidden bf16 reuses b4 (aw dead).
  unsigned short* hid = (unsigned short*)b4;
  for (int c = 0; c < 5; c++) {
    size_t ro = (size_t)c * FFN_CHUNK;
    gemm_mfma<false, 2><<<dim3(FFN_CHUNK / 128, 8), 256, 0, stream>>>(
        b3 + ro * 256, nullptr, wfc1T, b_fc1, nullptr, hid,
        FFN_CHUNK, 1024, 256);
    gemm_mfma<false, 3><<<dim3(FFN_CHUNK / 128, 2), 256, 0, stream>>>(
        hid, nullptr, wfc2T, b_fc2, b5 + ro * 256, out + ro * 256,
        FFN_CHUNK, 256, 1024);
  }
}

// Round 6
// 743.918 us; speedup vs baseline: 2.6336x; 1.1542x over previous
//
#include <hip/hip_runtime.h>

// MSDeformAttn encoder layer — bf16 MFMA GEMMs (global_load_lds staging) +
// two-phase deformable sampling (round-3 value path, register-staged gathers).
#define DMODEL 256
#define NHEAD 8
#define NPOINT 4
#define NLEVEL 4
#define DHEAD 32
#define MLPD 1024
#define BSZ 2
#define LQTOK 21760
#define NTOK (BSZ * LQTOK)  // 43520
#define LNEPS 1e-6f
#define FFN_CHUNK 21760     // NTOK/2, divisible by 128

typedef __attribute__((ext_vector_type(8))) short short8;
typedef __attribute__((ext_vector_type(4))) float f32x4;

__device__ __forceinline__ float bf2f(unsigned short u) {
  unsigned int i = ((unsigned int)u) << 16;
  return __builtin_bit_cast(float, i);
}
__device__ __forceinline__ unsigned short f2bf(float f) {
  unsigned int i = __builtin_bit_cast(unsigned int, f);
  i += 0x7fff + ((i >> 16) & 1);  // round-to-nearest-even
  return (unsigned short)(i >> 16);
}

// async global->LDS, 16B per lane; lds dest = wave-uniform base + lane*16
__device__ __forceinline__ void gload_lds16(const unsigned short* g,
                                            unsigned short* lds) {
  __builtin_amdgcn_global_load_lds(
      (const __attribute__((address_space(1))) unsigned int*)g,
      (__attribute__((address_space(3))) unsigned int*)lds, 16, 0, 0);
}

// ---------------- block reduction (256 threads = 4 waves) ----------------
__device__ __forceinline__ float block_reduce_sum(float v, float* sbuf) {
#pragma unroll
  for (int off = 32; off > 0; off >>= 1) v += __shfl_down(v, off, 64);
  int lane = threadIdx.x & 63;
  int w = threadIdx.x >> 6;
  if (lane == 0) sbuf[w] = v;
  __syncthreads();
  if (threadIdx.x == 0) sbuf[4] = sbuf[0] + sbuf[1] + sbuf[2] + sbuf[3];
  __syncthreads();
  return sbuf[4];
}

// ---------------- layernorm: o_bf16 = LN(in)*g + beta ----------------
__global__ __launch_bounds__(256) void ln_bf16(const float* __restrict__ in,
                                               const float* __restrict__ g,
                                               const float* __restrict__ beta,
                                               unsigned short* __restrict__ o) {
  __shared__ float sbuf[8];
  int t = blockIdx.x;
  int c = threadIdx.x;
  size_t base = (size_t)t * DMODEL + c;
  float v = in[base];
  float s = block_reduce_sum(v, sbuf);
  float mu = s * (1.0f / DMODEL);
  float d = v - mu;
  float s2 = block_reduce_sum(d * d, sbuf);
  float rs = rsqrtf(s2 * (1.0f / DMODEL) + LNEPS);
  o[base] = f2bf(d * rs * g[c] + beta[c]);
}

// ---------------- transpose + cast: Wt[n][k] = bf16(W[k][n]) ----------------
__global__ __launch_bounds__(256) void transpose_bf16(const float* __restrict__ W,
                                                      unsigned short* __restrict__ Wt,
                                                      int K, int N) {
  __shared__ float tile[32][33];
  int k0 = blockIdx.x * 32, n0 = blockIdx.y * 32;
  int tx = threadIdx.x & 31, ty = threadIdx.x >> 5;  // 32 x 8
  for (int i = ty; i < 32; i += 8) tile[i][tx] = W[(size_t)(k0 + i) * N + n0 + tx];
  __syncthreads();
  for (int i = ty; i < 32; i += 8)
    Wt[(size_t)(n0 + i) * K + k0 + tx] = f2bf(tile[tx][i]);
}

// ---------------- bf16 MFMA GEMM: C = (A[+pos]) @ Wt^T + bias [...] --------
// Tile 128x128, BK=32, 256 threads = 4 waves (2x2 of 64x64), 4x4 MFMA
// 16x16x32 per wave. A: bf16 [M][K]. Wt: bf16 [N][K]. Unpadded pitch-32 LDS
// (m97 layout — required by global_load_lds). OMODE: 0=f32, 1=bf16,
// 2=bf16+relu, 3=f32+res.
template <bool ADDPOS, int OMODE>
__global__ __launch_bounds__(256) void gemm_mfma(
    const unsigned short* __restrict__ A, const float* __restrict__ pos,
    const unsigned short* __restrict__ Wt, const float* __restrict__ bias,
    const float* __restrict__ res, void* __restrict__ Cout, int M, int N,
    int K) {
  __shared__ __attribute__((aligned(16))) unsigned short As[128 * 32];
  __shared__ __attribute__((aligned(16))) unsigned short Bs[128 * 32];
  const int tid = threadIdx.x;
  const int m0 = blockIdx.x * 128, n0 = blockIdx.y * 128;
  const int wave = tid >> 6, lane = tid & 63;
  const int wm = (wave & 1) * 64, wn = (wave >> 1) * 64;
  const int lr = lane & 15, quad = lane >> 4;
  f32x4 acc[4][4] = {};
  for (int k0 = 0; k0 < K; k0 += 32) {
    __syncthreads();
#pragma unroll
    for (int r = 0; r < 2; r++) {
      int c = r * 256 + tid;
      int row = c >> 2, col8 = (c & 3) * 8;
      gload_lds16(Wt + (size_t)(n0 + row) * K + k0 + col8,
                  &Bs[(r * 256 + wave * 64) * 8]);
    }
    if (!ADDPOS) {
#pragma unroll
      for (int r = 0; r < 2; r++) {
        int c = r * 256 + tid;
        int row = c >> 2, col8 = (c & 3) * 8;
        gload_lds16(A + (size_t)(m0 + row) * K + k0 + col8,
                    &As[(r * 256 + wave * 64) * 8]);
      }
    } else {
#pragma unroll
      for (int r = 0; r < 2; r++) {
        int s = tid + 256 * r;
        int row = s >> 2, c8 = (s & 3) * 8;
        const unsigned short* ga = A + (size_t)(m0 + row) * K + k0 + c8;
        const float* gp = pos + (size_t)(m0 + row) * K + k0 + c8;
        float4 p0 = *(const float4*)gp;
        float4 p1 = *(const float4*)(gp + 4);
        short8 xv = *(const short8*)ga;
        short8 ov;
        ov[0] = (short)f2bf(bf2f((unsigned short)xv[0]) + p0.x);
        ov[1] = (short)f2bf(bf2f((unsigned short)xv[1]) + p0.y);
        ov[2] = (short)f2bf(bf2f((unsigned short)xv[2]) + p0.z);
        ov[3] = (short)f2bf(bf2f((unsigned short)xv[3]) + p0.w);
        ov[4] = (short)f2bf(bf2f((unsigned short)xv[4]) + p1.x);
        ov[5] = (short)f2bf(bf2f((unsigned short)xv[5]) + p1.y);
        ov[6] = (short)f2bf(bf2f((unsigned short)xv[6]) + p1.z);
        ov[7] = (short)f2bf(bf2f((unsigned short)xv[7]) + p1.w);
        *(short8*)(&As[row * 32 + c8]) = ov;
      }
    }
    __syncthreads();
    short8 af[4], bfr[4];
#pragma unroll
    for (int i = 0; i < 4; i++)
      af[i] = *(const short8*)(&As[(wm + i * 16 + lr) * 32 + quad * 8]);
#pragma unroll
    for (int j = 0; j < 4; j++)
      bfr[j] = *(const short8*)(&Bs[(wn + j * 16 + lr) * 32 + quad * 8]);
#pragma unroll
    for (int i = 0; i < 4; i++)
#pragma unroll
      for (int j = 0; j < 4; j++)
        acc[i][j] = __builtin_amdgcn_mfma_f32_16x16x32_bf16(af[i], bfr[j],
                                                            acc[i][j], 0, 0, 0);
  }
  // epilogue: C/D layout col=lane&15, row=quad*4+reg
#pragma unroll
  for (int i = 0; i < 4; i++) {
    int rbase = m0 + wm + i * 16 + quad * 4;
#pragma unroll
    for (int j = 0; j < 4; j++) {
      int col = n0 + wn + j * 16 + lr;
      float bv = bias[col];
#pragma unroll
      for (int r = 0; r < 4; r++) {
        size_t idx = (size_t)(rbase + r) * N + col;
        float v = acc[i][j][r] + bv;
        if (OMODE == 2) v = fmaxf(v, 0.0f);
        if (OMODE == 3) v += res[idx];
        if (OMODE == 0 || OMODE == 3)
          ((float*)Cout)[idx] = v;
        else
          ((unsigned short*)Cout)[idx] = f2bf(v);
      }
    }
  }
}

// ---------------- softmax over last-16 (per b,q,h row), f32 in place -------
__global__ __launch_bounds__(256) void softmax16(float* __restrict__ E) {
  int r = blockIdx.x * 256 + threadIdx.x;
  if (r >= NTOK * NHEAD) return;
  float* p = E + (size_t)r * 16;
  float vals[16];
  float m = -1e30f;
#pragma unroll
  for (int i = 0; i < 16; i++) {
    vals[i] = p[i];
    m = fmaxf(m, vals[i]);
  }
  float s = 0.f;
#pragma unroll
  for (int i = 0; i < 16; i++) {
    vals[i] = expf(vals[i] - m);
    s += vals[i];
  }
  float inv = 1.0f / s;
#pragma unroll
  for (int i = 0; i < 16; i++) p[i] = vals[i] * inv;
}

// ---------------- deformable sampling, two-phase (round-3 value path) ------
// Phase 1: threads 0..127, one per (h,l,p): 4 clamped flat indices + 4
// aw-prescaled masked weights -> LDS (round-3 layout, verbatim).
// Phase 2: thread = h*32+d: 16 points in chunks of 4 — stage 8 LDS rows +
// 16 scalar gathers into registers, THEN consume with fmaf in round-3's
// exact (pt asc, corner x,y,z,w) order. FP-identical to round 3; only load
// scheduling differs (16 loads in flight vs ~4).
__global__ __launch_bounds__(256) void deform_sample(
    const unsigned short* __restrict__ val, const unsigned short* __restrict__ off,
    const float* __restrict__ aw, const float* __restrict__ refp,
    unsigned short* __restrict__ out) {
  __shared__ __attribute__((aligned(16))) int sIdx[128][4];
  __shared__ __attribute__((aligned(16))) float sW[128][4];
  int bq = blockIdx.x;
  int b = bq / LQTOK;
  int t = threadIdx.x;
  if (t < 128) {
    const int HW_[4] = {128, 64, 32, 16};
    const int LSI_[4] = {0, 16384, 20480, 21504};
    int h = t >> 4, l = (t >> 2) & 3;
    int HW = HW_[l];
    float rx = refp[(size_t)bq * 8 + l * 2 + 0];
    float ry = refp[(size_t)bq * 8 + l * 2 + 1];
    unsigned int ov = *(const unsigned int*)&off[(size_t)bq * 256 + 2 * t];
    float x = fmaf(rx, (float)HW, bf2f((unsigned short)(ov & 0xffff))) - 0.5f;
    float y = fmaf(ry, (float)HW, bf2f((unsigned short)(ov >> 16))) - 0.5f;
    float xf = floorf(x), yf = floorf(y);
    int x0 = (int)xf, y0 = (int)yf;
    float lx = x - xf, ly = y - yf;
    int x0c = min(max(x0, 0), HW - 1);
    int x1c = min(max(x0 + 1, 0), HW - 1);
    int y0c = min(max(y0, 0), HW - 1);
    int y1c = min(max(y0 + 1, 0), HW - 1);
    float mx0 = (x0 >= 0 && x0 < HW) ? 1.f : 0.f;
    float mx1 = (x0 + 1 >= 0 && x0 + 1 < HW) ? 1.f : 0.f;
    float my0 = (y0 >= 0 && y0 < HW) ? 1.f : 0.f;
    float my1 = (y0 + 1 >= 0 && y0 + 1 < HW) ? 1.f : 0.f;
    float a = aw[(size_t)bq * 128 + t];
    int hb = h * DHEAD;
    sIdx[t][0] = (LSI_[l] + y0c * HW + x0c) * DMODEL + hb;
    sIdx[t][1] = (LSI_[l] + y0c * HW + x1c) * DMODEL + hb;
    sIdx[t][2] = (LSI_[l] + y1c * HW + x0c) * DMODEL + hb;
    sIdx[t][3] = (LSI_[l] + y1c * HW + x1c) * DMODEL + hb;
    sW[t][0] = (1.f - lx) * (1.f - ly) * mx0 * my0 * a;
    sW[t][1] = lx * (1.f - ly) * mx1 * my0 * a;
    sW[t][2] = (1.f - lx) * ly * mx0 * my1 * a;
    sW[t][3] = lx * ly * mx1 * my1 * a;
  }
  __syncthreads();
  int h = t >> 5, d = t & 31;
  const unsigned short* vb = val + (size_t)b * LQTOK * DMODEL + d;
  float acc = 0.f;
#pragma unroll
  for (int c = 0; c < 4; c++) {
    // stage the 4 points' tables
    int4 ix[4];
    float4 w[4];
#pragma unroll
    for (int p = 0; p < 4; p++) {
      ix[p] = *(const int4*)sIdx[h * 16 + c * 4 + p];
      w[p] = *(const float4*)sW[h * 16 + c * 4 + p];
    }
    // issue all 16 gathers before consuming
    float v[4][4];
#pragma unroll
    for (int p = 0; p < 4; p++) {
      v[p][0] = bf2f(vb[ix[p].x]);
      v[p][1] = bf2f(vb[ix[p].y]);
      v[p][2] = bf2f(vb[ix[p].z]);
      v[p][3] = bf2f(vb[ix[p].w]);
    }
    // consume in round-3's exact order
#pragma unroll
    for (int p = 0; p < 4; p++) {
      acc = fmaf(w[p].x, v[p][0], acc);
      acc = fmaf(w[p].y, v[p][1], acc);
      acc = fmaf(w[p].z, v[p][2], acc);
      acc = fmaf(w[p].w, v[p][3], acc);
    }
  }
  out[(size_t)bq * DMODEL + t] = f2bf(acc);
}

// ---------------- launch ----------------
extern "C" void kernel_launch(void* const* d_in, const int* in_sizes, int n_in,
                              void* d_out, int out_size, void* d_ws,
                              size_t ws_size, hipStream_t stream) {
  const float* src    = (const float*)d_in[0];
  const float* pos    = (const float*)d_in[1];
  const float* refp   = (const float*)d_in[2];
  const float* g1     = (const float*)d_in[5];
  const float* beta1  = (const float*)d_in[6];
  const float* w_off  = (const float*)d_in[7];
  const float* b_off  = (const float*)d_in[8];
  const float* w_attn = (const float*)d_in[9];
  const float* b_attn = (const float*)d_in[10];
  const float* w_val  = (const float*)d_in[11];
  const float* b_val  = (const float*)d_in[12];
  const float* w_out  = (const float*)d_in[13];
  const float* b_out  = (const float*)d_in[14];
  const float* g2     = (const float*)d_in[15];
  const float* beta2  = (const float*)d_in[16];
  const float* w_fc1  = (const float*)d_in[17];
  const float* b_fc1  = (const float*)d_in[18];
  const float* w_fc2  = (const float*)d_in[19];
  const float* b_fc2  = (const float*)d_in[20];
  float* out = (float*)d_out;

  // Workspace: 135.2 MB total.
  const size_t NT = (size_t)NTOK;
  unsigned short* b1 = (unsigned short*)d_ws;  // x bf16 -> sampled -> ffn hid
  unsigned short* b2 = b1 + NT * 256;          // val bf16        -> ffn hid
  unsigned short* b3 = b2 + NT * 256;          // off bf16 -> y bf16
  float* b4 = (float*)(b3 + NT * 256);         // aw f32
  float* b5 = b4 + NT * 128;                   // src2 f32
  unsigned short* wvalT  = (unsigned short*)(b5 + NT * 256);  // [256][256]
  unsigned short* woffT  = wvalT + 256 * 256;                 // [256][256]
  unsigned short* wattnT = woffT + 256 * 256;                 // [128][256]
  unsigned short* woutT  = wattnT + 128 * 256;                // [256][256]
  unsigned short* wfc1T  = woutT + 256 * 256;                 // [1024][256]
  unsigned short* wfc2T  = wfc1T + 1024 * 256;                // [256][1024]

  // 0. weight transposes (f32 -> bf16, [K][N] -> [N][K]) — round-3 verbatim
  transpose_bf16<<<dim3(8, 8), 256, 0, stream>>>(w_val, wvalT, 256, 256);
  transpose_bf16<<<dim3(8, 8), 256, 0, stream>>>(w_off, woffT, 256, 256);
  transpose_bf16<<<dim3(8, 4), 256, 0, stream>>>(w_attn, wattnT, 256, 128);
  transpose_bf16<<<dim3(8, 8), 256, 0, stream>>>(w_out, woutT, 256, 256);
  transpose_bf16<<<dim3(8, 32), 256, 0, stream>>>(w_fc1, wfc1T, 256, 1024);
  transpose_bf16<<<dim3(32, 8), 256, 0, stream>>>(w_fc2, wfc2T, 1024, 256);

  const int MT = NTOK / 128;  // 340

  // 1. x = LN(src) -> bf16
  ln_bf16<<<NTOK, 256, 0, stream>>>(src, g1, beta1, b1);
  // 2. val = x @ w_val + b_val -> bf16
  gemm_mfma<false, 1><<<dim3(MT, 2), 256, 0, stream>>>(
      b1, nullptr, wvalT, b_val, nullptr, b2, NTOK, 256, 256);
  // 3. off = (x+pos) @ w_off + b_off -> bf16
  gemm_mfma<true, 1><<<dim3(MT, 2), 256, 0, stream>>>(
      b1, pos, woffT, b_off, nullptr, b3, NTOK, 256, 256);
  // 4. logits = (x+pos) @ w_attn + b_attn -> f32
  gemm_mfma<true, 0><<<dim3(MT, 1), 256, 0, stream>>>(
      b1, pos, wattnT, b_attn, nullptr, b4, NTOK, 128, 256);
  // 5. softmax over 16
  softmax16<<<(NTOK * NHEAD + 255) / 256, 256, 0, stream>>>(b4);
  // 6. sampling -> b1 (x dead); 1 token per block (round-3 mapping)
  deform_sample<<<NTOK, 256, 0, stream>>>(b2, b3, b4, refp, b1);
  // 7. src2 = sampled @ w_out + b_out + src -> f32
  gemm_mfma<false, 3><<<dim3(MT, 2), 256, 0, stream>>>(
      b1, nullptr, woutT, b_out, src, b5, NTOK, 256, 256);
  // 8. y = LN(src2) -> bf16 (off dead)
  ln_bf16<<<NTOK, 256, 0, stream>>>(b5, g2, beta2, b3);
  // 9/10. FFN in 2 chunks; hidden (21760x1024 bf16) exactly fills b1+b2
  // (both dead after step 7). Pure grid repartition vs round 3 — per-row
  // math identical.
  unsigned short* hid = b1;
  for (int c = 0; c < 2; c++) {
    size_t ro = (size_t)c * FFN_CHUNK;
    gemm_mfma<false, 2><<<dim3(FFN_CHUNK / 128, 8), 256, 0, stream>>>(
        b3 + ro * 256, nullptr, wfc1T, b_fc1, nullptr, hid,
        FFN_CHUNK, 1024, 256);
    gemm_mfma<false, 3><<<dim3(FFN_CHUNK / 128, 2), 256, 0, stream>>>(
        hid, nullptr, wfc2T, b_fc2, b5 + ro * 256, out + ro * 256,
        FFN_CHUNK, 256, 1024);
  }
}

// Round 7
// 539.880 us; speedup vs baseline: 3.6289x; 1.3779x over previous
//
#include <hip/hip_runtime.h>

// MSDeformAttn encoder layer — bf16 MFMA GEMMs (global_load_lds staging) +
// point-split uint2-gather deformable sampling with fused softmax.
#define DMODEL 256
#define NHEAD 8
#define NPOINT 4
#define NLEVEL 4
#define DHEAD 32
#define MLPD 1024
#define BSZ 2
#define LQTOK 21760
#define NTOK (BSZ * LQTOK)  // 43520
#define LNEPS 1e-6f
#define FFN_CHUNK 21760     // NTOK/2, divisible by 128

typedef __attribute__((ext_vector_type(8))) short short8;
typedef __attribute__((ext_vector_type(4))) float f32x4;

__device__ __forceinline__ float bf2f(unsigned short u) {
  unsigned int i = ((unsigned int)u) << 16;
  return __builtin_bit_cast(float, i);
}
__device__ __forceinline__ unsigned short f2bf(float f) {
  unsigned int i = __builtin_bit_cast(unsigned int, f);
  i += 0x7fff + ((i >> 16) & 1);  // round-to-nearest-even
  return (unsigned short)(i >> 16);
}
__device__ __forceinline__ float bflo(unsigned int u) {
  return __builtin_bit_cast(float, u << 16);
}
__device__ __forceinline__ float bfhi(unsigned int u) {
  return __builtin_bit_cast(float, u & 0xffff0000u);
}

// async global->LDS, 16B per lane; lds dest = wave-uniform base + lane*16
__device__ __forceinline__ void gload_lds16(const unsigned short* g,
                                            unsigned short* lds) {
  __builtin_amdgcn_global_load_lds(
      (const __attribute__((address_space(1))) unsigned int*)g,
      (__attribute__((address_space(3))) unsigned int*)lds, 16, 0, 0);
}

// ---------------- block reduction (256 threads = 4 waves) ----------------
__device__ __forceinline__ float block_reduce_sum(float v, float* sbuf) {
#pragma unroll
  for (int off = 32; off > 0; off >>= 1) v += __shfl_down(v, off, 64);
  int lane = threadIdx.x & 63;
  int w = threadIdx.x >> 6;
  if (lane == 0) sbuf[w] = v;
  __syncthreads();
  if (threadIdx.x == 0) sbuf[4] = sbuf[0] + sbuf[1] + sbuf[2] + sbuf[3];
  __syncthreads();
  return sbuf[4];
}

// ---------------- layernorm: o_bf16 = LN(in)*g + beta ----------------
__global__ __launch_bounds__(256) void ln_bf16(const float* __restrict__ in,
                                               const float* __restrict__ g,
                                               const float* __restrict__ beta,
                                               unsigned short* __restrict__ o) {
  __shared__ float sbuf[8];
  int t = blockIdx.x;
  int c = threadIdx.x;
  size_t base = (size_t)t * DMODEL + c;
  float v = in[base];
  float s = block_reduce_sum(v, sbuf);
  float mu = s * (1.0f / DMODEL);
  float d = v - mu;
  float s2 = block_reduce_sum(d * d, sbuf);
  float rs = rsqrtf(s2 * (1.0f / DMODEL) + LNEPS);
  o[base] = f2bf(d * rs * g[c] + beta[c]);
}

// ---------------- transpose + cast: Wt[n][k] = bf16(W[k][n]) ----------------
__global__ __launch_bounds__(256) void transpose_bf16(const float* __restrict__ W,
                                                      unsigned short* __restrict__ Wt,
                                                      int K, int N) {
  __shared__ float tile[32][33];
  int k0 = blockIdx.x * 32, n0 = blockIdx.y * 32;
  int tx = threadIdx.x & 31, ty = threadIdx.x >> 5;  // 32 x 8
  for (int i = ty; i < 32; i += 8) tile[i][tx] = W[(size_t)(k0 + i) * N + n0 + tx];
  __syncthreads();
  for (int i = ty; i < 32; i += 8)
    Wt[(size_t)(n0 + i) * K + k0 + tx] = f2bf(tile[tx][i]);
}

// ---------------- bf16 MFMA GEMM: C = (A[+pos]) @ Wt^T + bias [...] --------
// Tile 128x128, BK=32, 256 threads = 4 waves (2x2 of 64x64), 4x4 MFMA
// 16x16x32 per wave. A: bf16 [M][K]. Wt: bf16 [N][K]. Unpadded pitch-32 LDS
// (m97 layout — required by global_load_lds). OMODE: 0=f32, 1=bf16,
// 2=bf16+relu, 3=f32+res.
template <bool ADDPOS, int OMODE>
__global__ __launch_bounds__(256) void gemm_mfma(
    const unsigned short* __restrict__ A, const float* __restrict__ pos,
    const unsigned short* __restrict__ Wt, const float* __restrict__ bias,
    const float* __restrict__ res, void* __restrict__ Cout, int M, int N,
    int K) {
  __shared__ __attribute__((aligned(16))) unsigned short As[128 * 32];
  __shared__ __attribute__((aligned(16))) unsigned short Bs[128 * 32];
  const int tid = threadIdx.x;
  const int m0 = blockIdx.x * 128, n0 = blockIdx.y * 128;
  const int wave = tid >> 6, lane = tid & 63;
  const int wm = (wave & 1) * 64, wn = (wave >> 1) * 64;
  const int lr = lane & 15, quad = lane >> 4;
  f32x4 acc[4][4] = {};
  for (int k0 = 0; k0 < K; k0 += 32) {
    __syncthreads();
#pragma unroll
    for (int r = 0; r < 2; r++) {
      int c = r * 256 + tid;
      int row = c >> 2, col8 = (c & 3) * 8;
      gload_lds16(Wt + (size_t)(n0 + row) * K + k0 + col8,
                  &Bs[(r * 256 + wave * 64) * 8]);
    }
    if (!ADDPOS) {
#pragma unroll
      for (int r = 0; r < 2; r++) {
        int c = r * 256 + tid;
        int row = c >> 2, col8 = (c & 3) * 8;
        gload_lds16(A + (size_t)(m0 + row) * K + k0 + col8,
                    &As[(r * 256 + wave * 64) * 8]);
      }
    } else {
#pragma unroll
      for (int r = 0; r < 2; r++) {
        int s = tid + 256 * r;
        int row = s >> 2, c8 = (s & 3) * 8;
        const unsigned short* ga = A + (size_t)(m0 + row) * K + k0 + c8;
        const float* gp = pos + (size_t)(m0 + row) * K + k0 + c8;
        float4 p0 = *(const float4*)gp;
        float4 p1 = *(const float4*)(gp + 4);
        short8 xv = *(const short8*)ga;
        short8 ov;
        ov[0] = (short)f2bf(bf2f((unsigned short)xv[0]) + p0.x);
        ov[1] = (short)f2bf(bf2f((unsigned short)xv[1]) + p0.y);
        ov[2] = (short)f2bf(bf2f((unsigned short)xv[2]) + p0.z);
        ov[3] = (short)f2bf(bf2f((unsigned short)xv[3]) + p0.w);
        ov[4] = (short)f2bf(bf2f((unsigned short)xv[4]) + p1.x);
        ov[5] = (short)f2bf(bf2f((unsigned short)xv[5]) + p1.y);
        ov[6] = (short)f2bf(bf2f((unsigned short)xv[6]) + p1.z);
        ov[7] = (short)f2bf(bf2f((unsigned short)xv[7]) + p1.w);
        *(short8*)(&As[row * 32 + c8]) = ov;
      }
    }
    __syncthreads();
    short8 af[4], bfr[4];
#pragma unroll
    for (int i = 0; i < 4; i++)
      af[i] = *(const short8*)(&As[(wm + i * 16 + lr) * 32 + quad * 8]);
#pragma unroll
    for (int j = 0; j < 4; j++)
      bfr[j] = *(const short8*)(&Bs[(wn + j * 16 + lr) * 32 + quad * 8]);
#pragma unroll
    for (int i = 0; i < 4; i++)
#pragma unroll
      for (int j = 0; j < 4; j++)
        acc[i][j] = __builtin_amdgcn_mfma_f32_16x16x32_bf16(af[i], bfr[j],
                                                            acc[i][j], 0, 0, 0);
  }
  // epilogue: C/D layout col=lane&15, row=quad*4+reg
#pragma unroll
  for (int i = 0; i < 4; i++) {
    int rbase = m0 + wm + i * 16 + quad * 4;
#pragma unroll
    for (int j = 0; j < 4; j++) {
      int col = n0 + wn + j * 16 + lr;
      float bv = bias[col];
#pragma unroll
      for (int r = 0; r < 4; r++) {
        size_t idx = (size_t)(rbase + r) * N + col;
        float v = acc[i][j][r] + bv;
        if (OMODE == 2) v = fmaxf(v, 0.0f);
        if (OMODE == 3) v += res[idx];
        if (OMODE == 0 || OMODE == 3)
          ((float*)Cout)[idx] = v;
        else
          ((unsigned short*)Cout)[idx] = f2bf(v);
      }
    }
  }
}

// ---------------- deformable sampling + fused softmax ----------------
// Phase 1 (threads 0..127, one per (h,l,p)): softmax over each head's 16
// logits via 16-lane shfl butterflies, then 4 clamped flat indices + 4
// softmax-prescaled masked bilinear weights -> LDS.
// Phase 2: thread = (h, pp, g): pp splits the 16 points into 4 groups of 4,
// g is a 4-channel group (uint2 gathers, 8B). 16 independent gathers per
// thread; pp-partials combined by 2 shfl_xor butterflies (exact adds).
__global__ __launch_bounds__(256) void deform_sample(
    const unsigned short* __restrict__ val, const unsigned short* __restrict__ off,
    const float* __restrict__ logits, const float* __restrict__ refp,
    unsigned short* __restrict__ out) {
  __shared__ __attribute__((aligned(16))) int sIdx[128][4];
  __shared__ __attribute__((aligned(16))) float sW[128][4];
  int bq = blockIdx.x;
  int b = bq / LQTOK;
  int t = threadIdx.x;
  if (t < 128) {
    const int HW_[4] = {128, 64, 32, 16};
    const int LSI_[4] = {0, 16384, 20480, 21504};
    int h = t >> 4, l = (t >> 2) & 3;
    int HW = HW_[l];
    float rx = refp[(size_t)bq * 8 + l * 2 + 0];
    float ry = refp[(size_t)bq * 8 + l * 2 + 1];
    unsigned int ov = *(const unsigned int*)&off[(size_t)bq * 256 + 2 * t];
    float x = fmaf(rx, (float)HW, bf2f((unsigned short)(ov & 0xffff))) - 0.5f;
    float y = fmaf(ry, (float)HW, bf2f((unsigned short)(ov >> 16))) - 0.5f;
    float xf = floorf(x), yf = floorf(y);
    int x0 = (int)xf, y0 = (int)yf;
    float lx = x - xf, ly = y - yf;
    int x0c = min(max(x0, 0), HW - 1);
    int x1c = min(max(x0 + 1, 0), HW - 1);
    int y0c = min(max(y0, 0), HW - 1);
    int y1c = min(max(y0 + 1, 0), HW - 1);
    float mx0 = (x0 >= 0 && x0 < HW) ? 1.f : 0.f;
    float mx1 = (x0 + 1 >= 0 && x0 + 1 < HW) ? 1.f : 0.f;
    float my0 = (y0 >= 0 && y0 < HW) ? 1.f : 0.f;
    float my1 = (y0 + 1 >= 0 && y0 + 1 < HW) ? 1.f : 0.f;
    // fused softmax over this head's 16 logits (lanes t..t|15 in-wave)
    float lg = logits[(size_t)bq * 128 + t];
    float mx = lg;
#pragma unroll
    for (int s = 1; s < 16; s <<= 1) mx = fmaxf(mx, __shfl_xor(mx, s, 64));
    float e = expf(lg - mx);
    float ssum = e;
#pragma unroll
    for (int s = 1; s < 16; s <<= 1) ssum += __shfl_xor(ssum, s, 64);
    float a = e * (1.0f / ssum);
    int hb = h * DHEAD;
    sIdx[t][0] = (LSI_[l] + y0c * HW + x0c) * DMODEL + hb;
    sIdx[t][1] = (LSI_[l] + y0c * HW + x1c) * DMODEL + hb;
    sIdx[t][2] = (LSI_[l] + y1c * HW + x0c) * DMODEL + hb;
    sIdx[t][3] = (LSI_[l] + y1c * HW + x1c) * DMODEL + hb;
    sW[t][0] = (1.f - lx) * (1.f - ly) * mx0 * my0 * a;
    sW[t][1] = lx * (1.f - ly) * mx1 * my0 * a;
    sW[t][2] = (1.f - lx) * ly * mx0 * my1 * a;
    sW[t][3] = lx * ly * mx1 * my1 * a;
  }
  __syncthreads();
  int h = t >> 5;          // 0..7
  int pp = (t >> 3) & 3;   // point group 0..3
  int g = t & 7;           // 4-channel group 0..7
  const unsigned short* vb = val + (size_t)b * LQTOK * DMODEL + g * 4;
  int4 ix[4];
  float4 w[4];
#pragma unroll
  for (int p = 0; p < 4; p++) {
    ix[p] = *(const int4*)sIdx[h * 16 + pp * 4 + p];
    w[p] = *(const float4*)sW[h * 16 + pp * 4 + p];
  }
  uint2 v[4][4];
#pragma unroll
  for (int p = 0; p < 4; p++) {
    v[p][0] = *(const uint2*)(vb + ix[p].x);
    v[p][1] = *(const uint2*)(vb + ix[p].y);
    v[p][2] = *(const uint2*)(vb + ix[p].z);
    v[p][3] = *(const uint2*)(vb + ix[p].w);
  }
  float a0 = 0.f, a1 = 0.f, a2 = 0.f, a3 = 0.f;
#pragma unroll
  for (int p = 0; p < 4; p++) {
    float wk[4] = {w[p].x, w[p].y, w[p].z, w[p].w};
#pragma unroll
    for (int k = 0; k < 4; k++) {
      uint2 u = v[p][k];
      a0 = fmaf(wk[k], bflo(u.x), a0);
      a1 = fmaf(wk[k], bfhi(u.x), a1);
      a2 = fmaf(wk[k], bflo(u.y), a2);
      a3 = fmaf(wk[k], bfhi(u.y), a3);
    }
  }
  // combine the 4 point-group partials (exact adds, in-wave butterflies)
  a0 += __shfl_xor(a0, 8, 64);  a0 += __shfl_xor(a0, 16, 64);
  a1 += __shfl_xor(a1, 8, 64);  a1 += __shfl_xor(a1, 16, 64);
  a2 += __shfl_xor(a2, 8, 64);  a2 += __shfl_xor(a2, 16, 64);
  a3 += __shfl_xor(a3, 8, 64);  a3 += __shfl_xor(a3, 16, 64);
  if (pp == 0) {
    unsigned int o0 = ((unsigned int)f2bf(a1) << 16) | f2bf(a0);
    unsigned int o1 = ((unsigned int)f2bf(a3) << 16) | f2bf(a2);
    *(uint2*)(out + (size_t)bq * 256 + h * 32 + g * 4) = make_uint2(o0, o1);
  }
}

// ---------------- launch ----------------
extern "C" void kernel_launch(void* const* d_in, const int* in_sizes, int n_in,
                              void* d_out, int out_size, void* d_ws,
                              size_t ws_size, hipStream_t stream) {
  const float* src    = (const float*)d_in[0];
  const float* pos    = (const float*)d_in[1];
  const float* refp   = (const float*)d_in[2];
  const float* g1     = (const float*)d_in[5];
  const float* beta1  = (const float*)d_in[6];
  const float* w_off  = (const float*)d_in[7];
  const float* b_off  = (const float*)d_in[8];
  const float* w_attn = (const float*)d_in[9];
  const float* b_attn = (const float*)d_in[10];
  const float* w_val  = (const float*)d_in[11];
  const float* b_val  = (const float*)d_in[12];
  const float* w_out  = (const float*)d_in[13];
  const float* b_out  = (const float*)d_in[14];
  const float* g2     = (const float*)d_in[15];
  const float* beta2  = (const float*)d_in[16];
  const float* w_fc1  = (const float*)d_in[17];
  const float* b_fc1  = (const float*)d_in[18];
  const float* w_fc2  = (const float*)d_in[19];
  const float* b_fc2  = (const float*)d_in[20];
  float* out = (float*)d_out;

  // Workspace: 135.2 MB total.
  const size_t NT = (size_t)NTOK;
  unsigned short* b1 = (unsigned short*)d_ws;  // x bf16 -> sampled -> ffn hid
  unsigned short* b2 = b1 + NT * 256;          // val bf16        -> ffn hid
  unsigned short* b3 = b2 + NT * 256;          // off bf16 -> y bf16
  float* b4 = (float*)(b3 + NT * 256);         // attn logits f32
  float* b5 = b4 + NT * 128;                   // src2 f32
  unsigned short* wvalT  = (unsigned short*)(b5 + NT * 256);  // [256][256]
  unsigned short* woffT  = wvalT + 256 * 256;                 // [256][256]
  unsigned short* wattnT = woffT + 256 * 256;                 // [128][256]
  unsigned short* woutT  = wattnT + 128 * 256;                // [256][256]
  unsigned short* wfc1T  = woutT + 256 * 256;                 // [1024][256]
  unsigned short* wfc2T  = wfc1T + 1024 * 256;                // [256][1024]

  // 0. weight transposes (f32 -> bf16, [K][N] -> [N][K])
  transpose_bf16<<<dim3(8, 8), 256, 0, stream>>>(w_val, wvalT, 256, 256);
  transpose_bf16<<<dim3(8, 8), 256, 0, stream>>>(w_off, woffT, 256, 256);
  transpose_bf16<<<dim3(8, 4), 256, 0, stream>>>(w_attn, wattnT, 256, 128);
  transpose_bf16<<<dim3(8, 8), 256, 0, stream>>>(w_out, woutT, 256, 256);
  transpose_bf16<<<dim3(8, 32), 256, 0, stream>>>(w_fc1, wfc1T, 256, 1024);
  transpose_bf16<<<dim3(32, 8), 256, 0, stream>>>(w_fc2, wfc2T, 1024, 256);

  const int MT = NTOK / 128;  // 340

  // 1. x = LN(src) -> bf16
  ln_bf16<<<NTOK, 256, 0, stream>>>(src, g1, beta1, b1);
  // 2. val = x @ w_val + b_val -> bf16
  gemm_mfma<false, 1><<<dim3(MT, 2), 256, 0, stream>>>(
      b1, nullptr, wvalT, b_val, nullptr, b2, NTOK, 256, 256);
  // 3. off = (x+pos) @ w_off + b_off -> bf16
  gemm_mfma<true, 1><<<dim3(MT, 2), 256, 0, stream>>>(
      b1, pos, woffT, b_off, nullptr, b3, NTOK, 256, 256);
  // 4. logits = (x+pos) @ w_attn + b_attn -> f32 (softmax fused into sampler)
  gemm_mfma<true, 0><<<dim3(MT, 1), 256, 0, stream>>>(
      b1, pos, wattnT, b_attn, nullptr, b4, NTOK, 128, 256);
  // 5. sampling (with fused softmax) -> b1 (x dead)
  deform_sample<<<NTOK, 256, 0, stream>>>(b2, b3, b4, refp, b1);
  // 6. src2 = sampled @ w_out + b_out + src -> f32
  gemm_mfma<false, 3><<<dim3(MT, 2), 256, 0, stream>>>(
      b1, nullptr, woutT, b_out, src, b5, NTOK, 256, 256);
  // 7. y = LN(src2) -> bf16 (off dead)
  ln_bf16<<<NTOK, 256, 0, stream>>>(b5, g2, beta2, b3);
  // 8/9. FFN in 2 chunks; hidden (21760x1024 bf16) exactly fills b1+b2.
  unsigned short* hid = b1;
  for (int c = 0; c < 2; c++) {
    size_t ro = (size_t)c * FFN_CHUNK;
    gemm_mfma<false, 2><<<dim3(FFN_CHUNK / 128, 8), 256, 0, stream>>>(
        b3 + ro * 256, nullptr, wfc1T, b_fc1, nullptr, hid,
        FFN_CHUNK, 1024, 256);
    gemm_mfma<false, 3><<<dim3(FFN_CHUNK / 128, 2), 256, 0, stream>>>(
        hid, nullptr, wfc2T, b_fc2, b5 + ro * 256, out + ro * 256,
        FFN_CHUNK, 256, 1024);
  }
}